// Round 1
// baseline (198.976 us; speedup 1.0000x reference)
//
#include <hip/hip_runtime.h>
#include <math.h>

// Problem constants (from reference):
//   B=64, T=512, D=1024, VOCAB=50257
// Outputs: y[B,D] then y_hat[B,D], concatenated fp32 in d_out.
constexpr int B = 64;
constexpr int T = 512;
constexpr int D = 1024;
constexpr int NT = 16;            // t-chunks per batch row
constexpr int CHUNK = T / NT;     // 32 rows per block

// K1: each block handles (b, t-chunk). 256 threads x float4 covers the full
// D=1024 row per iteration (4KB contiguous, coalesced). Accumulate masked sum
// s and weighted sum y_hat in registers, atomically add into d_out.
__global__ __launch_bounds__(256) void k1_partial(
    const float* __restrict__ vs,      // [B,T,D]
    const int*   __restrict__ slen,    // [B]
    const int*   __restrict__ words,   // [B,T]
    const float* __restrict__ wts,     // [VOCAB]
    float*       __restrict__ out)     // [2,B,D] (zero-initialized)
{
    const int bid = blockIdx.x;
    const int b  = bid & (B - 1);      // bid % 64 — spreads b across consecutive blocks
    const int tc = bid >> 6;           // bid / 64
    const int len = slen[b];
    const int t0 = tc * CHUNK;
    if (t0 >= len) return;             // whole chunk masked out
    const int t1 = (t0 + CHUNK < len) ? (t0 + CHUNK) : len;

    __shared__ float wbuf[CHUNK];
    const int tid = threadIdx.x;
    if (tid < CHUNK) {
        const int t = t0 + tid;
        // gather per-token scalar weight; zero beyond len (unused anyway)
        wbuf[tid] = (t < len) ? wts[words[b * T + t]] : 0.0f;
    }
    __syncthreads();

    const int d0 = tid * 4;
    const float4* vp = (const float4*)(vs + ((size_t)(b * T + t0)) * D + d0);
    float4 s  = make_float4(0.f, 0.f, 0.f, 0.f);
    float4 yh = make_float4(0.f, 0.f, 0.f, 0.f);

    for (int t = t0; t < t1; ++t) {
        const float4 v = *vp;
        vp += D / 4;                   // advance one row
        const float w = wbuf[t - t0];  // uniform across block -> LDS broadcast (free)
        s.x += v.x; s.y += v.y; s.z += v.z; s.w += v.w;
        yh.x += v.x * w; yh.y += v.y * w; yh.z += v.z * w; yh.w += v.w * w;
    }

    float* so = out + (size_t)b * D + d0;            // s -> y slot (normalized by K2)
    float* yo = out + (size_t)(B + b) * D + d0;      // y_hat slot (final)
    atomicAdd(so + 0, s.x);  atomicAdd(so + 1, s.y);
    atomicAdd(so + 2, s.z);  atomicAdd(so + 3, s.w);
    atomicAdd(yo + 0, yh.x); atomicAdd(yo + 1, yh.y);
    atomicAdd(yo + 2, yh.z); atomicAdd(yo + 3, yh.w);
}

// K2: one block per b. Reduce sum_d |s[b,d]| across the block (D=1024 = 256
// threads x float4), then normalize in place: y = s / sqrt(sum|s|).
__global__ __launch_bounds__(256) void k2_normalize(float* __restrict__ out)
{
    const int b = blockIdx.x;
    const int tid = threadIdx.x;
    float* sp = out + (size_t)b * D + tid * 4;
    const float4 s = *(const float4*)sp;

    float a = fabsf(s.x) + fabsf(s.y) + fabsf(s.z) + fabsf(s.w);
    // wave (64-lane) butterfly reduce
    for (int off = 32; off > 0; off >>= 1)
        a += __shfl_down(a, off, 64);

    __shared__ float part[4];
    const int wave = tid >> 6;
    const int lane = tid & 63;
    if (lane == 0) part[wave] = a;
    __syncthreads();
    const float tot = part[0] + part[1] + part[2] + part[3];
    const float inv = 1.0f / sqrtf(tot);

    float4 y;
    y.x = s.x * inv; y.y = s.y * inv; y.z = s.z * inv; y.w = s.w * inv;
    *(float4*)sp = y;
}

extern "C" void kernel_launch(void* const* d_in, const int* in_sizes, int n_in,
                              void* d_out, int out_size, void* d_ws, size_t ws_size,
                              hipStream_t stream) {
    const float* vs    = (const float*)d_in[0];   // [B,T,D] fp32
    const int*   slen  = (const int*)  d_in[1];   // [B]
    const int*   words = (const int*)  d_in[2];   // [B,T]
    const float* wts   = (const float*)d_in[3];   // [VOCAB]
    float* out = (float*)d_out;                   // [2*B*D] fp32

    // d_out is re-poisoned to 0xAA before every timed launch; we accumulate
    // into it, so zero it first (async memset is graph-capture safe).
    hipMemsetAsync(out, 0, (size_t)2 * B * D * sizeof(float), stream);

    k1_partial<<<B * NT, 256, 0, stream>>>(vs, slen, words, wts, out);
    k2_normalize<<<B, 256, 0, stream>>>(out);
}

// Round 2
// 186.916 us; speedup vs baseline: 1.0645x; 1.0645x over previous
//
#include <hip/hip_runtime.h>
#include <math.h>

// Problem constants (from reference):
//   B=64, T=512, D=1024, VOCAB=50257
// Outputs: y[B,D] then y_hat[B,D], concatenated fp32 in d_out.
constexpr int B = 64;
constexpr int T = 512;
constexpr int D = 1024;
constexpr int NT = 16;            // t-chunks per batch row
constexpr int CHUNK = T / NT;     // 32 rows per block

// d_ws layout: partials[NT][B][2*D] fp32 = 8 MB.
//   partials[tc][b][0:D]   = sum over chunk tc of vs rows      (s partial)
//   partials[tc][b][D:2D]  = sum over chunk tc of vs*w rows    (y_hat partial)
// Chunks with tc*CHUNK >= len[b] are never written; k2 computes the active
// chunk count from len[b] and never reads the poisoned regions.

// K1: block = (b, t-chunk). 256 threads x float4 = full 4KB D-row per
// iteration, coalesced. Register accumulation, one coalesced 8KB write.
__global__ __launch_bounds__(256) void k1_partial(
    const float* __restrict__ vs,      // [B,T,D]
    const int*   __restrict__ slen,    // [B]
    const int*   __restrict__ words,   // [B,T]
    const float* __restrict__ wts,     // [VOCAB]
    float*       __restrict__ part)    // [NT][B][2*D] workspace
{
    const int bid = blockIdx.x;
    const int b  = bid & (B - 1);      // spread b across consecutive blocks
    const int tc = bid >> 6;
    const int len = slen[b];
    const int t0 = tc * CHUNK;
    if (t0 >= len) return;             // whole chunk masked out; never read by k2
    const int t1 = (t0 + CHUNK < len) ? (t0 + CHUNK) : len;

    __shared__ float wbuf[CHUNK];
    const int tid = threadIdx.x;
    if (tid < CHUNK) {
        const int t = t0 + tid;
        wbuf[tid] = (t < len) ? wts[words[b * T + t]] : 0.0f;
    }
    __syncthreads();

    const int d0 = tid * 4;
    const float4* vp = (const float4*)(vs + ((size_t)(b * T + t0)) * D + d0);
    float4 s  = make_float4(0.f, 0.f, 0.f, 0.f);
    float4 yh = make_float4(0.f, 0.f, 0.f, 0.f);

    #pragma unroll 4
    for (int t = t0; t < t1; ++t) {
        const float4 v = *vp;
        vp += D / 4;                   // next row
        const float w = wbuf[t - t0];  // block-uniform -> LDS broadcast
        s.x += v.x; s.y += v.y; s.z += v.z; s.w += v.w;
        yh.x += v.x * w; yh.y += v.y * w; yh.z += v.z * w; yh.w += v.w * w;
    }

    float* p = part + ((size_t)tc * B + b) * (2 * D) + d0;
    *(float4*)p       = s;
    *(float4*)(p + D) = yh;
}

// K2: one block per b. Sum active partials, reduce sum|s| across the block,
// write y = s/sqrt(sum|s|) and y_hat to d_out.
__global__ __launch_bounds__(256) void k2_finalize(
    const float* __restrict__ part,    // [NT][B][2*D]
    const int*   __restrict__ slen,    // [B]
    float*       __restrict__ out)     // [2,B,D]
{
    const int b = blockIdx.x;
    const int tid = threadIdx.x;
    const int len = slen[b];
    const int nact = (len + CHUNK - 1) / CHUNK;   // active chunks, >= 1

    const int d0 = tid * 4;
    float4 s  = make_float4(0.f, 0.f, 0.f, 0.f);
    float4 yh = make_float4(0.f, 0.f, 0.f, 0.f);
    for (int tc = 0; tc < nact; ++tc) {
        const float* p = part + ((size_t)tc * B + b) * (2 * D) + d0;
        const float4 ps = *(const float4*)p;
        const float4 py = *(const float4*)(p + D);
        s.x += ps.x; s.y += ps.y; s.z += ps.z; s.w += ps.w;
        yh.x += py.x; yh.y += py.y; yh.z += py.z; yh.w += py.w;
    }

    float a = fabsf(s.x) + fabsf(s.y) + fabsf(s.z) + fabsf(s.w);
    for (int off = 32; off > 0; off >>= 1)
        a += __shfl_down(a, off, 64);

    __shared__ float psum[4];
    const int wave = tid >> 6;
    const int lane = tid & 63;
    if (lane == 0) psum[wave] = a;
    __syncthreads();
    const float tot = psum[0] + psum[1] + psum[2] + psum[3];
    const float inv = 1.0f / sqrtf(tot);

    float4 y;
    y.x = s.x * inv; y.y = s.y * inv; y.z = s.z * inv; y.w = s.w * inv;
    *(float4*)(out + (size_t)b * D + d0)       = y;   // y
    *(float4*)(out + (size_t)(B + b) * D + d0) = yh;  // y_hat
}

extern "C" void kernel_launch(void* const* d_in, const int* in_sizes, int n_in,
                              void* d_out, int out_size, void* d_ws, size_t ws_size,
                              hipStream_t stream) {
    const float* vs    = (const float*)d_in[0];   // [B,T,D] fp32
    const int*   slen  = (const int*)  d_in[1];   // [B]
    const int*   words = (const int*)  d_in[2];   // [B,T]
    const float* wts   = (const float*)d_in[3];   // [VOCAB]
    float* out  = (float*)d_out;                  // [2*B*D] fp32
    float* part = (float*)d_ws;                   // [NT][B][2*D] = 8 MB

    k1_partial <<<B * NT, 256, 0, stream>>>(vs, slen, words, wts, part);
    k2_finalize<<<B,      256, 0, stream>>>(part, slen, out);
}